// Round 4
// baseline (139.719 us; speedup 1.0000x reference)
//
#include <hip/hip_runtime.h>
#include <hip/hip_bf16.h>

#define NN   8192
#define INF_ 256
#define OUTF 128
#define SLOPE 0.2f
#define NJC  4              // j-chunks (blocks splitting the j dimension)
#define JCHUNK (NN / NJC)   // 2048
#define NT   (JCHUNK / 128) // 16 tiles of 128 j

typedef float f32x4  __attribute__((ext_vector_type(4)));
typedef float f32x16 __attribute__((ext_vector_type(16)));
typedef short bf16x8 __attribute__((ext_vector_type(8)));
typedef int   i32x4  __attribute__((ext_vector_type(4)));
typedef unsigned short u16;
typedef u16 u16x4 __attribute__((ext_vector_type(4)));

__device__ __forceinline__ u16 f2bf(float f) {
  return __builtin_bit_cast(u16, __float2bfloat16(f));
}

// ---------------------------------------------------------------------------
// K1: h = X @ W (fp32). Writes hbF (bf16, MFMA-B-fragment order), s1, s2.
// ---------------------------------------------------------------------------
__global__ __launch_bounds__(256) void gat_k1(
    const float* __restrict__ X, const float* __restrict__ W,
    const float* __restrict__ a, u16* __restrict__ hbF,
    float* __restrict__ s1, float* __restrict__ s2) {
  __shared__ float xs[32 * INF_];
  const int t = threadIdx.x;
  const int r0 = blockIdx.x * 32;
  {
    const f32x4* src = (const f32x4*)(X + (size_t)r0 * INF_);
    f32x4* dst = (f32x4*)xs;
    for (int i = t; i < 32 * INF_ / 4; i += 256) dst[i] = src[i];
  }
  __syncthreads();
  const int cg = t & 31;
  const int rg = t >> 5;
  float acc[4][4];
#pragma unroll
  for (int i = 0; i < 4; i++)
#pragma unroll
    for (int j = 0; j < 4; j++) acc[i][j] = 0.f;

  for (int k = 0; k < INF_; k += 4) {
    f32x4 xv[4];
#pragma unroll
    for (int i = 0; i < 4; i++) xv[i] = *(const f32x4*)&xs[(rg * 4 + i) * INF_ + k];
#pragma unroll
    for (int kk = 0; kk < 4; kk++) {
      f32x4 wv = *(const f32x4*)&W[(k + kk) * OUTF + cg * 4];
#pragma unroll
      for (int i = 0; i < 4; i++)
#pragma unroll
        for (int j = 0; j < 4; j++) acc[i][j] = fmaf(xv[i][kk], wv[j], acc[i][j]);
    }
  }

  f32x4 a1v = *(const f32x4*)&a[cg * 4];
  f32x4 a2v = *(const f32x4*)&a[OUTF + cg * 4];
  float p1[4], p2[4];
#pragma unroll
  for (int i = 0; i < 4; i++) {
    p1[i] = acc[i][0] * a1v[0] + acc[i][1] * a1v[1] + acc[i][2] * a1v[2] + acc[i][3] * a1v[3];
    p2[i] = acc[i][0] * a2v[0] + acc[i][1] * a2v[1] + acc[i][2] * a2v[2] + acc[i][3] * a2v[3];
  }
#pragma unroll
  for (int m = 1; m < 32; m <<= 1) {
#pragma unroll
    for (int i = 0; i < 4; i++) {
      p1[i] += __shfl_xor(p1[i], m);
      p2[i] += __shfl_xor(p2[i], m);
    }
  }
  if (cg == 0) {
#pragma unroll
    for (int i = 0; i < 4; i++) {
      s1[r0 + rg * 4 + i] = p1[i];
      s2[r0 + rg * 4 + i] = p2[i];
    }
  }

  const int R0 = r0 + rg * 4;
  const int J  = R0 >> 4;
  const int gg = (R0 >> 3) & 1;
  const int e0 = R0 & 7;
#pragma unroll
  for (int j = 0; j < 4; j++) {
    const int C = cg * 4 + j;
    u16x4 pk;
#pragma unroll
    for (int i = 0; i < 4; i++) pk[i] = f2bf(acc[i][j]);
    size_t flat = ((size_t)(J * 4 + (C >> 5)) * 64 + (C & 31) + 32 * gg) * 8 + e0;
    *(u16x4*)(hbF + flat) = pk;
  }
}

// ---------------------------------------------------------------------------
// K2: s2max = max(s2)
// ---------------------------------------------------------------------------
__global__ __launch_bounds__(256) void gat_k2(const float* __restrict__ s2,
                                              float* __restrict__ s2m) {
  __shared__ float sm[4];
  const int t = threadIdx.x;
  float m = -1e30f;
  for (int i = t; i < NN; i += 256) m = fmaxf(m, s2[i]);
#pragma unroll
  for (int k = 1; k < 64; k <<= 1) m = fmaxf(m, __shfl_xor(m, k));
  if ((t & 63) == 0) sm[t >> 6] = m;
  __syncthreads();
  if (t == 0) *s2m = fmaxf(fmaxf(sm[0], sm[1]), fmaxf(sm[2], sm[3]));
}

// ---------------------------------------------------------------------------
// K3: fused mask+lrelu+exp+PV over a 32-row x 2048-j slice. NO barriers in
// the main loop: each wave loads its own MFMA-A adj ints straight to the
// owning lanes (L1 absorbs the partial-line overlap between sibling waves),
// so waves slide freely and the compiler pipelines the loads.
// Grid 1024 = 256 row-groups x 4 j-chunks; 512 threads (8 waves, 4 blk/CU).
// ---------------------------------------------------------------------------
__device__ __forceinline__ void st16(float* dst, const f32x16& A, int g) {
#pragma unroll
  for (int r = 0; r < 16; r++) {
    const int dr = (r & 3) + 8 * (r >> 2) + 4 * g;
    dst[dr * 128] = A[r];
  }
}
__device__ __forceinline__ void ad16(float* dst, const f32x16& A, int g) {
#pragma unroll
  for (int r = 0; r < 16; r++) {
    const int dr = (r & 3) + 8 * (r >> 2) + 4 * g;
    dst[dr * 128] += A[r];
  }
}

__global__ __launch_bounds__(512, 4) void gat_k3(
    const int* __restrict__ adj, const u16* __restrict__ hbF,
    const float* __restrict__ s1g, const float* __restrict__ s2g,
    const float* __restrict__ s2maxp, float* __restrict__ part,
    float* __restrict__ dpart) {
  __shared__ float lred[8192];   // 32 KB, epilogue only
  __shared__ float dred[256];
  const int t = threadIdx.x;
  const int w = t >> 6;
  const int l = t & 63;
  const int rb = blockIdx.x & 255;
  const int jc = blockIdx.x >> 8;
  const int r0 = rb * 32;
  const int j0 = jc * JCHUNK;
  const int row = l & 31;
  const int g = l >> 5;

  const float s1r = s1g[r0 + row];
  const float s2m = *s2maxp;
  float Mi = s1r + s2m;
  Mi = fmaxf(Mi, SLOPE * Mi);       // lrelu of upper bound >= all row scores
  const float ar = s1r - Mi;        // lrelu(x)-Mi = max(ar+s2, br+SLOPE*s2)
  const float br = SLOPE * s1r - Mi;

  f32x16 acc0 = 0.f, acc1 = 0.f, acc2 = 0.f, acc3 = 0.f;

  const int c0 = 16 * w + 8 * g;    // this lane's j-offset within a tile
  const int*    ap = adj + (size_t)(r0 + row) * NN + j0 + c0;
  const float*  sp = s2g + j0 + c0;
  const bf16x8* bp = (const bf16x8*)hbF + ((size_t)(jc * 128 + w) * 4) * 64 + l;

  float dsum = 0.f;
  for (int tt = 0; tt < NT; tt++) {
    i32x4 A0 = *(const i32x4*)(ap + 128 * tt);
    i32x4 A1 = *(const i32x4*)(ap + 128 * tt + 4);
    f32x4 s0  = *(const f32x4*)(sp + 128 * tt);
    f32x4 s1v = *(const f32x4*)(sp + 128 * tt + 4);
    const bf16x8* bq = bp + (size_t)tt * 8 * 4 * 64;
    bf16x8 b0 = bq[0], b1 = bq[64], b2 = bq[128], b3 = bq[192];

    bf16x8 af;
#pragma unroll
    for (int e = 0; e < 8; e++) {
      const float sv = (e < 4) ? s0[e] : s1v[e - 4];
      const float y = fmaxf(ar + sv, fmaf(SLOPE, sv, br));  // lrelu - Mi <= 0
      float p = __expf(y);
      const int ad = (e < 4) ? A0[e] : A1[e - 4];
      p = (ad > 0) ? p : 0.f;
      dsum += p;
      af[e] = (short)f2bf(p);
    }
    acc0 = __builtin_amdgcn_mfma_f32_32x32x16_bf16(af, b0, acc0, 0, 0, 0);
    acc1 = __builtin_amdgcn_mfma_f32_32x32x16_bf16(af, b1, acc1, 0, 0, 0);
    acc2 = __builtin_amdgcn_mfma_f32_32x32x16_bf16(af, b2, acc2, 0, 0, 0);
    acc3 = __builtin_amdgcn_mfma_f32_32x32x16_bf16(af, b3, acc3, 0, 0, 0);
  }

  // ---- denominator partial ----
  dsum += __shfl_xor(dsum, 32);
  if (l < 32) dred[w * 32 + l] = dsum;

  // ---- accumulator reduce across 8 waves into 2 LDS bufs (4 rounds) ----
  const int colw = l & 31;
  if (w < 2) {
    st16(&lred[w * 4096 + 0 * 32 + colw], acc0, g);
    st16(&lred[w * 4096 + 1 * 32 + colw], acc1, g);
    st16(&lred[w * 4096 + 2 * 32 + colw], acc2, g);
    st16(&lred[w * 4096 + 3 * 32 + colw], acc3, g);
  }
  __syncthreads();
  if (t < 32) {
    float d = 0.f;
#pragma unroll
    for (int w8 = 0; w8 < 8; w8++) d += dred[w8 * 32 + t];
    dpart[jc * NN + r0 + t] = d;
  }
  if (w == 2 || w == 3) {
    ad16(&lred[(w - 2) * 4096 + 0 * 32 + colw], acc0, g);
    ad16(&lred[(w - 2) * 4096 + 1 * 32 + colw], acc1, g);
    ad16(&lred[(w - 2) * 4096 + 2 * 32 + colw], acc2, g);
    ad16(&lred[(w - 2) * 4096 + 3 * 32 + colw], acc3, g);
  }
  __syncthreads();
  if (w == 4 || w == 5) {
    ad16(&lred[(w - 4) * 4096 + 0 * 32 + colw], acc0, g);
    ad16(&lred[(w - 4) * 4096 + 1 * 32 + colw], acc1, g);
    ad16(&lred[(w - 4) * 4096 + 2 * 32 + colw], acc2, g);
    ad16(&lred[(w - 4) * 4096 + 3 * 32 + colw], acc3, g);
  }
  __syncthreads();
  if (w == 6 || w == 7) {
    ad16(&lred[(w - 6) * 4096 + 0 * 32 + colw], acc0, g);
    ad16(&lred[(w - 6) * 4096 + 1 * 32 + colw], acc1, g);
    ad16(&lred[(w - 6) * 4096 + 2 * 32 + colw], acc2, g);
    ad16(&lred[(w - 6) * 4096 + 3 * 32 + colw], acc3, g);
  }
  __syncthreads();

  // ---- write fp32 partial: sum the 2 bufs ----
  const int flat = t * 8;  // row = t>>4, col = (t&15)*8
  f32x4 pa = *(f32x4*)&lred[flat];
  f32x4 pb = *(f32x4*)&lred[flat + 4];
  pa += *(f32x4*)&lred[4096 + flat];
  pb += *(f32x4*)&lred[4096 + flat + 4];
  float* pp = part + (size_t)jc * (NN * OUTF) + (size_t)r0 * OUTF + flat;
  *(f32x4*)pp = pa;
  *(f32x4*)(pp + 4) = pb;
}

// ---------------------------------------------------------------------------
// K4: combine 4 partials, divide by denom, elu, store.
// ---------------------------------------------------------------------------
__global__ __launch_bounds__(256) void gat_k4(
    const float* __restrict__ part, const float* __restrict__ dpart,
    float* __restrict__ out) {
  const int idx = blockIdx.x * 256 + threadIdx.x;
  const int e4 = idx * 4;
  const int i = e4 >> 7;
  f32x4 p = {0.f, 0.f, 0.f, 0.f};
  float d = 0.f;
#pragma unroll
  for (int jc = 0; jc < NJC; jc++) {
    p += *(const f32x4*)&part[(size_t)jc * (NN * OUTF) + e4];
    d += dpart[jc * NN + i];
  }
  d = fmaxf(d, 1e-30f);
  f32x4 r;
#pragma unroll
  for (int k = 0; k < 4; k++) {
    float v = p[k] / d;
    r[k] = (v > 0.f) ? v : expm1f(v);
  }
  *(f32x4*)&out[e4] = r;
}

extern "C" void kernel_launch(void* const* d_in, const int* in_sizes, int n_in,
                              void* d_out, int out_size, void* d_ws, size_t ws_size,
                              hipStream_t stream) {
  (void)in_sizes; (void)n_in; (void)out_size; (void)ws_size;
  const float* X  = (const float*)d_in[0];
  const int*  adj = (const int*)d_in[1];
  const float* W  = (const float*)d_in[2];
  const float* a  = (const float*)d_in[3];
  float* out = (float*)d_out;

  char* ws = (char*)d_ws;
  u16*   hbF   = (u16*)ws;                                  // 2 MB
  float* s1    = (float*)(ws + (2u << 20));                 // 32 KB
  float* s2    = (float*)(ws + (2u << 20) + (32u << 10));   // 32 KB
  float* s2m   = (float*)(ws + (2u << 20) + (64u << 10));   // 4 B
  float* dpart = (float*)(ws + (2u << 20) + (128u << 10));  // 128 KB
  float* part  = (float*)(ws + (4u << 20));                 // 16 MB

  gat_k1<<<NN / 32, 256, 0, stream>>>(X, W, a, hbF, s1, s2);
  gat_k2<<<1, 256, 0, stream>>>(s2, s2m);
  gat_k3<<<256 * NJC, 512, 0, stream>>>(adj, hbF, s1, s2, s2m, part, dpart);
  gat_k4<<<(NN * OUTF / 4) / 256, 256, 0, stream>>>(part, dpart, out);
}

// Round 5
// 113.822 us; speedup vs baseline: 1.2275x; 1.2275x over previous
//
#include <hip/hip_runtime.h>
#include <hip/hip_bf16.h>

#define NN   8192
#define INF_ 256
#define OUTF 128
#define SLOPE 0.2f
#define NJC  4              // j-chunks (blocks splitting the j dimension)
#define JCHUNK (NN / NJC)   // 2048
#define NT   (JCHUNK / 128) // 16 tiles of 128 j

typedef float f32x4  __attribute__((ext_vector_type(4)));
typedef float f32x16 __attribute__((ext_vector_type(16)));
typedef short bf16x8 __attribute__((ext_vector_type(8)));
typedef int   i32x4  __attribute__((ext_vector_type(4)));
typedef unsigned short u16;
typedef u16 u16x4 __attribute__((ext_vector_type(4)));

__device__ __forceinline__ u16 f2bf(float f) {
  return __builtin_bit_cast(u16, __float2bfloat16(f));
}

// ---------------------------------------------------------------------------
// K1: h = X @ W (fp32). Writes hbF (bf16, MFMA-B-fragment order), s1, s2.
// ---------------------------------------------------------------------------
__global__ __launch_bounds__(256) void gat_k1(
    const float* __restrict__ X, const float* __restrict__ W,
    const float* __restrict__ a, u16* __restrict__ hbF,
    float* __restrict__ s1, float* __restrict__ s2) {
  __shared__ float xs[32 * INF_];
  const int t = threadIdx.x;
  const int r0 = blockIdx.x * 32;
  {
    const f32x4* src = (const f32x4*)(X + (size_t)r0 * INF_);
    f32x4* dst = (f32x4*)xs;
    for (int i = t; i < 32 * INF_ / 4; i += 256) dst[i] = src[i];
  }
  __syncthreads();
  const int cg = t & 31;
  const int rg = t >> 5;
  float acc[4][4];
#pragma unroll
  for (int i = 0; i < 4; i++)
#pragma unroll
    for (int j = 0; j < 4; j++) acc[i][j] = 0.f;

  for (int k = 0; k < INF_; k += 4) {
    f32x4 xv[4];
#pragma unroll
    for (int i = 0; i < 4; i++) xv[i] = *(const f32x4*)&xs[(rg * 4 + i) * INF_ + k];
#pragma unroll
    for (int kk = 0; kk < 4; kk++) {
      f32x4 wv = *(const f32x4*)&W[(k + kk) * OUTF + cg * 4];
#pragma unroll
      for (int i = 0; i < 4; i++)
#pragma unroll
        for (int j = 0; j < 4; j++) acc[i][j] = fmaf(xv[i][kk], wv[j], acc[i][j]);
    }
  }

  f32x4 a1v = *(const f32x4*)&a[cg * 4];
  f32x4 a2v = *(const f32x4*)&a[OUTF + cg * 4];
  float p1[4], p2[4];
#pragma unroll
  for (int i = 0; i < 4; i++) {
    p1[i] = acc[i][0] * a1v[0] + acc[i][1] * a1v[1] + acc[i][2] * a1v[2] + acc[i][3] * a1v[3];
    p2[i] = acc[i][0] * a2v[0] + acc[i][1] * a2v[1] + acc[i][2] * a2v[2] + acc[i][3] * a2v[3];
  }
#pragma unroll
  for (int m = 1; m < 32; m <<= 1) {
#pragma unroll
    for (int i = 0; i < 4; i++) {
      p1[i] += __shfl_xor(p1[i], m);
      p2[i] += __shfl_xor(p2[i], m);
    }
  }
  if (cg == 0) {
#pragma unroll
    for (int i = 0; i < 4; i++) {
      s1[r0 + rg * 4 + i] = p1[i];
      s2[r0 + rg * 4 + i] = p2[i];
    }
  }

  const int R0 = r0 + rg * 4;
  const int J  = R0 >> 4;
  const int gg = (R0 >> 3) & 1;
  const int e0 = R0 & 7;
#pragma unroll
  for (int j = 0; j < 4; j++) {
    const int C = cg * 4 + j;
    u16x4 pk;
#pragma unroll
    for (int i = 0; i < 4; i++) pk[i] = f2bf(acc[i][j]);
    size_t flat = ((size_t)(J * 4 + (C >> 5)) * 64 + (C & 31) + 32 * gg) * 8 + e0;
    *(u16x4*)(hbF + flat) = pk;
  }
}

// ---------------------------------------------------------------------------
// K2: s2max = max(s2)
// ---------------------------------------------------------------------------
__global__ __launch_bounds__(256) void gat_k2(const float* __restrict__ s2,
                                              float* __restrict__ s2m) {
  __shared__ float sm[4];
  const int t = threadIdx.x;
  float m = -1e30f;
  for (int i = t; i < NN; i += 256) m = fmaxf(m, s2[i]);
#pragma unroll
  for (int k = 1; k < 64; k <<= 1) m = fmaxf(m, __shfl_xor(m, k));
  if ((t & 63) == 0) sm[t >> 6] = m;
  __syncthreads();
  if (t == 0) *s2m = fmaxf(fmaxf(sm[0], sm[1]), fmaxf(sm[2], sm[3]));
}

// ---------------------------------------------------------------------------
// K3: fused mask+lrelu+exp+PV over a 32-row x 2048-j slice.
// 2-phase pipeline (T3 recipe): per tile, FIRST issue global_load_lds for
// tile t+1 (coalesced; per-lane pre-swizzled global source -> linear LDS
// dest) and prefetch B-frags for t+1 into regs, THEN compute tile t from
// LDS (swizzled ds_read) + MFMA, then one barrier. The vmcnt(0) drain at
// the barrier lands after a full compute phase of latency cover.
// Grid 1024 = 256 row-groups x 4 j-chunks; 512 threads (8 waves, 4 blk/CU).
// ---------------------------------------------------------------------------
__device__ __forceinline__ void st16(float* dst, const f32x16& A, int g) {
#pragma unroll
  for (int r = 0; r < 16; r++) {
    const int dr = (r & 3) + 8 * (r >> 2) + 4 * g;
    dst[dr * 128] = A[r];
  }
}
__device__ __forceinline__ void ad16(float* dst, const f32x16& A, int g) {
#pragma unroll
  for (int r = 0; r < 16; r++) {
    const int dr = (r & 3) + 8 * (r >> 2) + 4 * g;
    dst[dr * 128] += A[r];
  }
}

__global__ __launch_bounds__(512, 4) void gat_k3(
    const int* __restrict__ adj, const u16* __restrict__ hbF,
    const float* __restrict__ s1g, const float* __restrict__ s2g,
    const float* __restrict__ s2maxp, float* __restrict__ part,
    float* __restrict__ dpart) {
  __shared__ int adjs[2 * 4096];   // 32 KB double-buffer; aliased in epilogue
  __shared__ float dred[256];
  const int t = threadIdx.x;
  const int w = t >> 6;
  const int l = t & 63;
  const int rb = blockIdx.x & 255;
  const int jc = blockIdx.x >> 8;
  const int r0 = rb * 32;
  const int j0 = jc * JCHUNK;
  const int row = l & 31;
  const int g = l >> 5;

  const float s1r = s1g[r0 + row];
  const float s2m = *s2maxp;
  float Mi = s1r + s2m;
  Mi = fmaxf(Mi, SLOPE * Mi);       // lrelu of upper bound >= all row scores
  const float ar = s1r - Mi;        // lrelu(x)-Mi = max(ar+s2, br+SLOPE*s2)
  const float br = SLOPE * s1r - Mi;

  f32x16 acc0 = 0.f, acc1 = 0.f, acc2 = 0.f, acc3 = 0.f;

  // ---- stage addressing: wave w owns rows 4w..4w+3; 2 gload_lds of 1 KB ----
  // LDS dest linear (hw: base + lane*16); global source pre-swizzled:
  // lane l -> row rr, colgroup (l&31)^rr, so LDS(row, slot) = col (slot^row).
  const int rr0 = 4 * w + (l >> 5);
  const int rr1 = rr0 + 2;
  const int cg0 = (l & 31) ^ rr0;
  const int cg1 = (l & 31) ^ rr1;
  const int* gs0 = adj + (size_t)(r0 + rr0) * NN + j0 + cg0 * 4;
  const int* gs1 = adj + (size_t)(r0 + rr1) * NN + j0 + cg1 * 4;
  int* lb0A = &adjs[(4 * w) * 128];
  int* lb1A = &adjs[(4 * w + 2) * 128];
  int* lb0B = lb0A + 4096;
  int* lb1B = lb1A + 4096;

#define STAGE(LB0, LB1, TL)                                                 \
  {                                                                         \
    __builtin_amdgcn_global_load_lds(                                       \
        (const __attribute__((address_space(1))) void*)(gs0 + (TL) * 128),  \
        (__attribute__((address_space(3))) void*)(LB0), 16, 0, 0);          \
    __builtin_amdgcn_global_load_lds(                                       \
        (const __attribute__((address_space(1))) void*)(gs1 + (TL) * 128),  \
        (__attribute__((address_space(3))) void*)(LB1), 16, 0, 0);          \
  }

  // ---- compute-side LDS read slots (full 5-bit XOR) ----
  const int c0 = 16 * w + 8 * g;    // this lane's j-offset within a tile
  const int sl0 = (((c0 >> 2) + 0) ^ row) & 31;
  const int sl1 = (((c0 >> 2) + 1) ^ row) & 31;

  const bf16x8* bp = (const bf16x8*)hbF + ((size_t)(jc * 128 + w) * 4) * 64 + l;
  const float* sp = s2g + j0 + c0;
  float dsum = 0.f;

  bf16x8 bA0, bA1, bA2, bA3, bB0, bB1, bB2, bB3;
#define LOADB(D0, D1, D2, D3, TL)                  \
  {                                                \
    const bf16x8* bq_ = bp + (size_t)(TL) * 2048;  \
    D0 = bq_[0];                                   \
    D1 = bq_[64];                                  \
    D2 = bq_[128];                                 \
    D3 = bq_[192];                                 \
  }

#define COMPUTE(TL, ABUF, B0, B1, B2, B3)                                 \
  {                                                                       \
    const int* ab_ = &adjs[(ABUF) * 4096 + row * 128];                    \
    i32x4 A0 = *(const i32x4*)(ab_ + sl0 * 4);                            \
    i32x4 A1 = *(const i32x4*)(ab_ + sl1 * 4);                            \
    f32x4 s0 = *(const f32x4*)(sp + 128 * (TL));                          \
    f32x4 s1v = *(const f32x4*)(sp + 128 * (TL) + 4);                     \
    bf16x8 af;                                                            \
    _Pragma("unroll") for (int e = 0; e < 8; e++) {                       \
      const float sv = (e < 4) ? s0[e] : s1v[e - 4];                      \
      const float y = fmaxf(ar + sv, fmaf(SLOPE, sv, br));                \
      float p = __expf(y);                                                \
      const int ad = (e < 4) ? A0[e] : A1[e - 4];                         \
      p = (ad > 0) ? p : 0.f;                                             \
      dsum += p;                                                          \
      af[e] = (short)f2bf(p);                                             \
    }                                                                     \
    acc0 = __builtin_amdgcn_mfma_f32_32x32x16_bf16(af, B0, acc0, 0, 0, 0);\
    acc1 = __builtin_amdgcn_mfma_f32_32x32x16_bf16(af, B1, acc1, 0, 0, 0);\
    acc2 = __builtin_amdgcn_mfma_f32_32x32x16_bf16(af, B2, acc2, 0, 0, 0);\
    acc3 = __builtin_amdgcn_mfma_f32_32x32x16_bf16(af, B3, acc3, 0, 0, 0);\
  }

  // ---- prologue: tile 0 into buf A; B-frags for tile 0 ----
  STAGE(lb0A, lb1A, 0);
  LOADB(bA0, bA1, bA2, bA3, 0);
  __syncthreads();

  for (int tt = 0; tt < NT; tt += 2) {
    // even body: stage tt+1 -> buf B, prefetch B(tt+1); compute tt from buf A
    if (tt + 1 < NT) {
      STAGE(lb0B, lb1B, tt + 1);
      LOADB(bB0, bB1, bB2, bB3, tt + 1);
    }
    COMPUTE(tt, 0, bA0, bA1, bA2, bA3);
    __syncthreads();

    // odd body: stage tt+2 -> buf A, prefetch B(tt+2); compute tt+1 from buf B
    if (tt + 2 < NT) {
      STAGE(lb0A, lb1A, tt + 2);
      LOADB(bA0, bA1, bA2, bA3, tt + 2);
    }
    COMPUTE(tt + 1, 1, bB0, bB1, bB2, bB3);
    __syncthreads();
  }

  // ---- denominator partial ----
  dsum += __shfl_xor(dsum, 32);
  if (l < 32) dred[w * 32 + l] = dsum;

  // ---- accumulator reduce across 8 waves into 2 LDS bufs (4 rounds) ----
  float* lred = (float*)adjs;
  const int colw = l & 31;
  if (w < 2) {
    st16(&lred[w * 4096 + 0 * 32 + colw], acc0, g);
    st16(&lred[w * 4096 + 1 * 32 + colw], acc1, g);
    st16(&lred[w * 4096 + 2 * 32 + colw], acc2, g);
    st16(&lred[w * 4096 + 3 * 32 + colw], acc3, g);
  }
  __syncthreads();
  if (t < 32) {
    float d = 0.f;
#pragma unroll
    for (int w8 = 0; w8 < 8; w8++) d += dred[w8 * 32 + t];
    dpart[jc * NN + r0 + t] = d;
  }
  if (w == 2 || w == 3) {
    ad16(&lred[(w - 2) * 4096 + 0 * 32 + colw], acc0, g);
    ad16(&lred[(w - 2) * 4096 + 1 * 32 + colw], acc1, g);
    ad16(&lred[(w - 2) * 4096 + 2 * 32 + colw], acc2, g);
    ad16(&lred[(w - 2) * 4096 + 3 * 32 + colw], acc3, g);
  }
  __syncthreads();
  if (w == 4 || w == 5) {
    ad16(&lred[(w - 4) * 4096 + 0 * 32 + colw], acc0, g);
    ad16(&lred[(w - 4) * 4096 + 1 * 32 + colw], acc1, g);
    ad16(&lred[(w - 4) * 4096 + 2 * 32 + colw], acc2, g);
    ad16(&lred[(w - 4) * 4096 + 3 * 32 + colw], acc3, g);
  }
  __syncthreads();
  if (w == 6 || w == 7) {
    ad16(&lred[(w - 6) * 4096 + 0 * 32 + colw], acc0, g);
    ad16(&lred[(w - 6) * 4096 + 1 * 32 + colw], acc1, g);
    ad16(&lred[(w - 6) * 4096 + 2 * 32 + colw], acc2, g);
    ad16(&lred[(w - 6) * 4096 + 3 * 32 + colw], acc3, g);
  }
  __syncthreads();

  // ---- write fp32 partial: sum the 2 bufs ----
  const int flat = t * 8;  // row = t>>4, col = (t&15)*8
  f32x4 pa = *(f32x4*)&lred[flat];
  f32x4 pb = *(f32x4*)&lred[flat + 4];
  pa += *(f32x4*)&lred[4096 + flat];
  pb += *(f32x4*)&lred[4096 + flat + 4];
  float* pp = part + (size_t)jc * (NN * OUTF) + (size_t)r0 * OUTF + flat;
  *(f32x4*)pp = pa;
  *(f32x4*)(pp + 4) = pb;
}

// ---------------------------------------------------------------------------
// K4: combine 4 partials, divide by denom, elu, store.
// ---------------------------------------------------------------------------
__global__ __launch_bounds__(256) void gat_k4(
    const float* __restrict__ part, const float* __restrict__ dpart,
    float* __restrict__ out) {
  const int idx = blockIdx.x * 256 + threadIdx.x;
  const int e4 = idx * 4;
  const int i = e4 >> 7;
  f32x4 p = {0.f, 0.f, 0.f, 0.f};
  float d = 0.f;
#pragma unroll
  for (int jc = 0; jc < NJC; jc++) {
    p += *(const f32x4*)&part[(size_t)jc * (NN * OUTF) + e4];
    d += dpart[jc * NN + i];
  }
  d = fmaxf(d, 1e-30f);
  f32x4 r;
#pragma unroll
  for (int k = 0; k < 4; k++) {
    float v = p[k] / d;
    r[k] = (v > 0.f) ? v : expm1f(v);
  }
  *(f32x4*)&out[e4] = r;
}

extern "C" void kernel_launch(void* const* d_in, const int* in_sizes, int n_in,
                              void* d_out, int out_size, void* d_ws, size_t ws_size,
                              hipStream_t stream) {
  (void)in_sizes; (void)n_in; (void)out_size; (void)ws_size;
  const float* X  = (const float*)d_in[0];
  const int*  adj = (const int*)d_in[1];
  const float* W  = (const float*)d_in[2];
  const float* a  = (const float*)d_in[3];
  float* out = (float*)d_out;

  char* ws = (char*)d_ws;
  u16*   hbF   = (u16*)ws;                                  // 2 MB
  float* s1    = (float*)(ws + (2u << 20));                 // 32 KB
  float* s2    = (float*)(ws + (2u << 20) + (32u << 10));   // 32 KB
  float* s2m   = (float*)(ws + (2u << 20) + (64u << 10));   // 4 B
  float* dpart = (float*)(ws + (2u << 20) + (128u << 10));  // 128 KB
  float* part  = (float*)(ws + (4u << 20));                 // 16 MB

  gat_k1<<<NN / 32, 256, 0, stream>>>(X, W, a, hbF, s1, s2);
  gat_k2<<<1, 256, 0, stream>>>(s2, s2m);
  gat_k3<<<256 * NJC, 512, 0, stream>>>(adj, hbF, s1, s2, s2m, part, dpart);
  gat_k4<<<(NN * OUTF / 4) / 256, 256, 0, stream>>>(part, dpart, out);
}